// Round 1
// 690.105 us; speedup vs baseline: 1.3746x; 1.3746x over previous
//
#include <hip/hip_runtime.h>

using f32x4  = __attribute__((ext_vector_type(4))) float;
using bf16x8 = __attribute__((ext_vector_type(8))) __bf16;

static constexpr int Bc = 8;     // batch
static constexpr int Nn = 2048;  // main graph nodes
static constexpr int Np = 1024;  // second graph nodes

// ---------------------------------------------------------------------------
// Z1^T (b, 288, 2048) bf16: layer-1 x@W concat (transposed). No pad anymore.
// ---------------------------------------------------------------------------
__global__ __launch_bounds__(256) void build_z1t_kernel(
    const float* __restrict__ x_n,
    const float* __restrict__ f0, const float* __restrict__ f1,
    const float* __restrict__ f2, const float* __restrict__ f3,
    const float* __restrict__ f4, const float* __restrict__ f5,
    const float* __restrict__ W_l1a, const float* __restrict__ W_l1b,
    __bf16* __restrict__ Z1T)
{
  int idx = blockIdx.x * 256 + threadIdx.x;   // total = 8*288*2048
  int n = idx & 2047;
  int t = idx >> 11;
  int c = t % 288;
  int b = t / 288;
  int g = c >> 5, h = c & 31;
  long long bn = ((long long)b << 11) | n;
  float s = 0.f;
  if (g < 3) {
    const float* x = x_n + bn * 6;
    const float* W = W_l1a + g * 192 + h;     // W_l1a[g][k][h]
    #pragma unroll
    for (int k = 0; k < 6; k++) s = fmaf(x[k], W[k * 32], s);
  } else {
    const float* fp;
    switch (g) { case 3: fp = f0; break; case 4: fp = f1; break;
                 case 5: fp = f2; break; case 6: fp = f3; break;
                 case 7: fp = f4; break; default: fp = f5; }
    const float* x = fp + bn * 3;
    const float* W = W_l1b + (g - 3) * 96 + h;
    #pragma unroll
    for (int k = 0; k < 3; k++) s = fmaf(x[k], W[k * 32], s);
  }
  Z1T[idx] = (__bf16)s;
}

// Zp^T (b, 32, 1024) bf16 = (x_p @ W_l1a[3])^T
__global__ __launch_bounds__(256) void build_zpt_kernel(
    const float* __restrict__ x_p, const float* __restrict__ W_l1a,
    __bf16* __restrict__ ZpT)
{
  int idx = blockIdx.x * 256 + threadIdx.x;   // total = 8*32*1024
  int n = idx & 1023;
  int t = idx >> 10;
  int h = t & 31;
  int b = t >> 5;
  const float* x = x_p + ((long long)(b << 10) + n) * 6;
  const float* W = W_l1a + 576 + h;           // W_l1a[3][k][h]
  float s = 0.f;
  #pragma unroll
  for (int k = 0; k < 6; k++) s = fmaf(x[k], W[k * 32], s);
  ZpT[idx] = (__bf16)s;
}

// bias288: layer-1 concat bias; biasg: layer-2 A_n group bias (storage order)
__global__ void build_bias_kernel(const float* __restrict__ b_l1a,
                                  const float* __restrict__ b_l1b,
                                  const float* __restrict__ b_l2,
                                  float* __restrict__ bias288,
                                  float* __restrict__ biasg)
{
  int t = threadIdx.x;
  if (t < 288) {
    int g = t >> 5, h = t & 31;
    bias288[t] = (g < 3) ? b_l1a[g * 32 + h] : b_l1b[(g - 3) * 32 + h];
  } else if (t < 288 + 256) {
    int c = t - 288;
    int g = c >> 5, h = c & 31;
    const int wsel[8] = {0, 4, 5, 6, 7, 8, 9, 10};
    biasg[c] = b_l2[wsel[g] * 32 + h];
  }
}

// ---------------------------------------------------------------------------
// Z2^T (b, 352, 2048) bf16 from post-relu bf16 Y1.
// ---------------------------------------------------------------------------
__global__ __launch_bounds__(256) void build_z2t_kernel(
    const __bf16* __restrict__ Y1bf, const float* __restrict__ pooled,
    const float* __restrict__ W_l2, __bf16* __restrict__ Z2T)
{
  __shared__ float Ys[32][289];
  const int b = blockIdx.y;
  const int n0 = blockIdx.x * 32;
  const int tid = threadIdx.x;
  const __bf16* Yb = Y1bf + ((size_t)(b * Nn) + n0) * 288;
  for (int i = tid; i < 32 * 36; i += 256) {   // 8-bf16 chunks
    int r = i / 36, c8 = (i % 36) * 8;
    bf16x8 v = *(const bf16x8*)(Yb + (size_t)r * 288 + c8);
    #pragma unroll
    for (int e = 0; e < 8; e++) Ys[r][c8 + e] = (float)v[e];
  }
  float pv = pooled[b * 32 + (n0 >> 6)];
  __syncthreads();
  int nl = tid & 31, cg = tid >> 5;
  for (int zc = cg; zc < 352; zc += 8) {
    int z = zc >> 5, h = zc & 31;
    constexpr int inoff[11] = {0, 96, 128, 160, 192, 224, 256, 0, 32, 32, 64};
    constexpr int wsel[11]  = {0, 4, 5, 6, 7, 8, 9, 10, 1, 2, 3};
    const float* W = W_l2 + wsel[z] * 1024 + h;   // W_l2[w][k][h]
    float s;
    if (z == 7) {
      float wsum = 0.f;
      #pragma unroll
      for (int k = 0; k < 32; k++) wsum += W[k * 32];
      s = pv * wsum;
    } else {
      const float* yr = &Ys[nl][inoff[z]];
      s = 0.f;
      #pragma unroll
      for (int k = 0; k < 32; k++) s = fmaf(yr[k], W[k * 32], s);
    }
    Z2T[((long long)(b * 352 + zc) << 11) + n0 + nl] = (__bf16)s;
  }
}

// ---------------------------------------------------------------------------
// Streaming MFMA GEMM core, latency-pipelined:
//  - BM=64 rows/block, 4 waves, wave = one 16-row M-tile, all NJM*16 cols.
//  - A: per-lane direct global->register fragment loads (row = lane&15,
//    kseg = lane>>4) -- A never touches LDS; fp32->bf16 cvt at use.
//  - B: global_load_lds into 3 LDS buffers, 2 tiles in flight (depth-2).
//    Bank-conflict XOR swizzle realized by pre-swizzling the GLOBAL source
//    address (gll dest is linear lane-order); ds_read side uses sw(row,seg)
//    = row*32 + ((seg^(row&3)^((row>>2)&3))&3)*8, same as proven layout.
//  - One raw s_barrier per K-step; counted s_waitcnt vmcnt(GMAX+2) (never 0
//    in steady state). Per-tile VMEM count is a compile-time constant
//    (TV = GMAX gll + 2 A-loads) so the waitcnt legalizer stays precise.
//  Buffer-cycle safety: tile k reads buf k%3; stage(k+2) -> (k+2)%3 happens
//  after barrier(k), and (k+2)%3 != k%3, (k+1)%3 -> no wave can touch it.
// ---------------------------------------------------------------------------
__device__ __forceinline__ void gload_lds16(const __bf16* src, __bf16* dst) {
  __builtin_amdgcn_global_load_lds(
      (const __attribute__((address_space(1))) void*)src,
      (__attribute__((address_space(3))) void*)dst, 16, 0, 0);
}

template<int BSTRIDE, int NJM, int GMAX, bool COLSUM>
__device__ __forceinline__ void gemm_core(
    const float* __restrict__ Ap, const __bf16* __restrict__ Bp,
    const float* __restrict__ bias, float* __restrict__ outp,
    __bf16* __restrict__ yout, int Kdim, int iters, __bf16* Bs)
{
  const int tid  = threadIdx.x;
  const int lane = tid & 63, wv = tid >> 6;
  const int lr = lane & 15, quad = lane >> 4;

  // B gll: lane l of a 1KB group holds (col = g*16 + l>>2, data-seg =
  // (l&3)^((l>>2)&3)^((l>>4)&3)) -- the inverse of the read-side XOR.
  const int colL = lane >> 2;
  const int segB = (lane & 3) ^ ((lane >> 2) & 3) ^ ((lane >> 4) & 3);
  const __bf16* Bsrc = Bp + (size_t)colL * Kdim + segB * 8;

  // A fragment source: lane reads A[m0 + wv*16 + (lane&15)][it*32 + quad*8 ..]
  const float* Asrc = Ap + (size_t)(wv * 16 + lr) * Kdim + quad * 8;

  // B fragment read offset (elements) within a group; + j*512 per group.
  const int xseg = (quad ^ (lr & 3) ^ ((lr >> 2) & 3)) & 3;
  const int boff = lr * 32 + xseg * 8;

  f32x4 acc[NJM];
  #pragma unroll
  for (int j = 0; j < NJM; j++) acc[j] = (f32x4){0.f, 0.f, 0.f, 0.f};

  auto stageB = [&](int it, int buf) {
    const __bf16* s0 = Bsrc + (size_t)it * 32;
    __bf16* d0 = Bs + buf * BSTRIDE;
    #pragma unroll
    for (int i = 0; i < GMAX; i++) {
      int g = wv + i * 4;
      if (g >= NJM) g -= NJM;   // wrap -> duplicate-stage (identical bytes, benign)
      gload_lds16(s0 + (size_t)g * 16 * Kdim, d0 + g * 512);
    }
  };
  auto loadA = [&](int it, f32x4& ra, f32x4& rb) {
    const float* s = Asrc + (size_t)it * 32;
    ra = *(const f32x4*)(s);
    rb = *(const f32x4*)(s + 4);
  };
  auto computeT = [&](int buf, f32x4 ra, f32x4 rb) {
    bf16x8 af;
    af[0]=(__bf16)ra[0]; af[1]=(__bf16)ra[1]; af[2]=(__bf16)ra[2]; af[3]=(__bf16)ra[3];
    af[4]=(__bf16)rb[0]; af[5]=(__bf16)rb[1]; af[6]=(__bf16)rb[2]; af[7]=(__bf16)rb[3];
    const __bf16* bb = Bs + buf * BSTRIDE + boff;
    #pragma unroll
    for (int j = 0; j < NJM; j++) {
      bf16x8 bv = *(const bf16x8*)(bb + j * 512);
      acc[j] = __builtin_amdgcn_mfma_f32_16x16x32_bf16(af, bv, acc[j], 0, 0, 0);
    }
  };

  constexpr int TVC = GMAX + 2;   // VMEM instrs per tile-stage (uniform, const)
  auto waitTV = [&]() {           // ensure oldest tile landed; keep newest in flight
    if constexpr (TVC == 7)      asm volatile("s_waitcnt vmcnt(7)" ::: "memory");
    else if constexpr (TVC == 6) asm volatile("s_waitcnt vmcnt(6)" ::: "memory");
    else                         asm volatile("s_waitcnt vmcnt(3)" ::: "memory");
    __builtin_amdgcn_sched_barrier(0);
    __builtin_amdgcn_s_barrier();
    __builtin_amdgcn_sched_barrier(0);
  };
  auto wait0 = [&]() {
    asm volatile("s_waitcnt vmcnt(0)" ::: "memory");
    __builtin_amdgcn_sched_barrier(0);
    __builtin_amdgcn_s_barrier();
    __builtin_amdgcn_sched_barrier(0);
  };

  // prologue: tiles 0,1 in flight
  f32x4 aE0, aE1, aO0, aO1;
  loadA(0, aE0, aE1); stageB(0, 0);
  loadA(1, aO0, aO1); stageB(1, 1);

  int bufR = 0;
  // steady loop: trip = iters-2 (even: iters is 64 or 32); no conditional VMEM
  for (int k = 0; k < iters - 2; k += 2) {
    waitTV();
    computeT(bufR, aE0, aE1);
    int w0 = bufR + 2; if (w0 >= 3) w0 -= 3;
    loadA(k + 2, aE0, aE1);
    stageB(k + 2, w0);

    int b1 = bufR + 1; if (b1 >= 3) b1 -= 3;
    waitTV();
    computeT(b1, aO0, aO1);
    loadA(k + 3, aO0, aO1);
    stageB(k + 3, bufR);        // (k+3)%3 == bufR
    bufR = w0;
  }
  // peeled tail: tiles iters-2 (E regs), iters-1 (O regs)
  waitTV();
  computeT(bufR, aE0, aE1);
  {
    int b1 = bufR + 1; if (b1 >= 3) b1 -= 3;
    wait0();
    computeT(b1, aO0, aO1);
  }

  if constexpr (!COLSUM) {
    // Y1 = relu(acc + bias) -> bf16 (288 cols exact)
    #pragma unroll
    for (int j = 0; j < NJM; j++) {
      int col = j * 16 + lr;
      float bvv = bias[col];
      #pragma unroll
      for (int r = 0; r < 4; r++) {
        int row = wv * 16 + quad * 4 + r;
        yout[(size_t)row * 288 + col] = (__bf16)fmaxf(acc[j][r] + bvv, 0.f);
      }
    }
  } else {
    #pragma unroll
    for (int j = 0; j < NJM; j++) {
      int col = j * 16 + lr;
      float bvv = bias[col];
      float s = 0.f;
      #pragma unroll
      for (int r = 0; r < 4; r++) s += fmaxf(acc[j][r] + bvv, 0.f);
      s += __shfl_xor(s, 16);
      s += __shfl_xor(s, 32);
      if (quad == 0) atomicAdd(&outp[col], s);
    }
  }
}

// phase 1: layer-1 main (Y1, 288 cols) + A_p (pooled). grid = 256+128.
// XCD-batch swizzle: b = id&7 so each XCD's L2 holds one batch's Z panel.
__global__ __launch_bounds__(256, 2) void mega0_kernel(
    const float* __restrict__ An, const float* __restrict__ Apm,
    const __bf16* __restrict__ Z1T, const __bf16* __restrict__ ZpT,
    const float* __restrict__ bias288, const float* __restrict__ biasAp,
    __bf16* __restrict__ Y1bf, float* __restrict__ pooled)
{
  __shared__ __align__(16) __bf16 Bs[3][288 * 32];
  int id = blockIdx.x;
  if (id < 256) {
    int b = id & 7, m0 = ((id >> 3) & 31) * 64;
    gemm_core<288 * 32, 18, 5, false>(
        An + ((size_t)b * Nn + m0) * Nn, Z1T + (size_t)b * 288 * Nn,
        bias288, nullptr, Y1bf + ((size_t)b * Nn + m0) * 288, Nn, Nn / 32,
        &Bs[0][0]);
  } else {
    int id2 = id - 256;
    int b = id2 & 7, m0 = (id2 >> 3) * 64;
    gemm_core<288 * 32, 2, 1, true>(
        Apm + ((size_t)b * Np + m0) * Np, ZpT + (size_t)b * 32 * Np,
        biasAp, pooled + b * 32, nullptr, Np, Np / 32, &Bs[0][0]);
  }
}

// phase 2: layer-2 A_n group (256 cols) + ts/cs/s (32 each). grid = 256+768.
__global__ __launch_bounds__(256, 2) void mega1_kernel(
    const float* __restrict__ An, const float* __restrict__ Ats,
    const float* __restrict__ Acs, const float* __restrict__ Asl,
    const __bf16* __restrict__ Z2T,
    const float* __restrict__ biasg, const float* __restrict__ bias2,
    float* __restrict__ p2)
{
  __shared__ __align__(16) __bf16 Bs[3][256 * 32];
  int id = blockIdx.x;
  if (id < 256) {
    int b = id & 7, m0 = ((id >> 3) & 31) * 64;
    gemm_core<256 * 32, 16, 4, true>(
        An + ((size_t)b * Nn + m0) * Nn, Z2T + (size_t)b * 352 * Nn,
        biasg, p2 + b * 352, nullptr, Nn, Nn / 32, &Bs[0][0]);
  } else {
    int id2 = id - 256;
    int which = id2 >> 8, r = id2 & 255;
    int b = r & 7, m0 = ((r >> 3) & 31) * 64;
    const float* Asel = (which == 0) ? Ats : (which == 1) ? Acs : Asl;
    gemm_core<256 * 32, 2, 1, true>(
        Asel + ((size_t)b * Nn + m0) * Nn,
        Z2T + (size_t)b * 352 * Nn + (size_t)(256 + 32 * which) * Nn,
        bias2 + 32 * which, p2 + b * 352 + 256 + 32 * which, nullptr,
        Nn, Nn / 32, &Bs[0][0]);
  }
}

// ---------------------------------------------------------------------------
// Final head: reorder pooled2 (storage order) -> pair order, then
// 352->128 relu, 128->128 relu, 128->1. One block, 128 threads.
// ---------------------------------------------------------------------------
__global__ __launch_bounds__(128) void final_mlp_kernel(
    const float* __restrict__ p2,
    const float* __restrict__ Wd1, const float* __restrict__ bd1,
    const float* __restrict__ Wd2, const float* __restrict__ bd2,
    const float* __restrict__ Wo,  const float* __restrict__ bo,
    float* __restrict__ outp)
{
  __shared__ float q [Bc][352];
  __shared__ float q1[Bc][128];
  __shared__ float q2[Bc][128];
  int t = threadIdx.x;
  const int map[11] = {0, 256, 288, 320, 32, 64, 96, 128, 160, 192, 224};
  for (int i = t; i < Bc * 352; i += 128) {
    int b = i / 352, c = i % 352;
    int p = c >> 5, h = c & 31;
    q[b][c] = p2[b * 352 + map[p] + h];
  }
  __syncthreads();
  for (int b = 0; b < Bc; b++) {
    float s = bd1[t];
    for (int i = 0; i < 352; i++) s = fmaf(q[b][i], Wd1[i * 128 + t], s);
    q1[b][t] = fmaxf(s, 0.f);
  }
  __syncthreads();
  for (int b = 0; b < Bc; b++) {
    float s = bd2[t];
    for (int i = 0; i < 128; i++) s = fmaf(q1[b][i], Wd2[i * 128 + t], s);
    q2[b][t] = fmaxf(s, 0.f);
  }
  __syncthreads();
  if (t < Bc) {
    float s = bo[0];
    for (int i = 0; i < 128; i++) s = fmaf(q2[t][i], Wo[i], s);
    outp[t] = s;
  }
}

// ---------------------------------------------------------------------------
extern "C" void kernel_launch(void* const* d_in, const int* in_sizes, int n_in,
                              void* d_out, int out_size, void* d_ws, size_t ws_size,
                              hipStream_t stream) {
  (void)in_sizes; (void)n_in; (void)out_size; (void)ws_size;
  const float* x_n   = (const float*)d_in[0];
  const float* A_n   = (const float*)d_in[1];
  const float* A_s   = (const float*)d_in[2];
  const float* A_ts  = (const float*)d_in[3];
  const float* A_cs  = (const float*)d_in[4];
  const float* x_p   = (const float*)d_in[6];
  const float* A_p   = (const float*)d_in[7];
  const float* fg0   = (const float*)d_in[8];
  const float* fg1   = (const float*)d_in[9];
  const float* fg2   = (const float*)d_in[10];
  const float* fg3   = (const float*)d_in[11];
  const float* fg4   = (const float*)d_in[12];
  const float* fg5   = (const float*)d_in[13];
  const float* W_l1a = (const float*)d_in[14];
  const float* b_l1a = (const float*)d_in[15];
  const float* W_l1b = (const float*)d_in[16];
  const float* b_l1b = (const float*)d_in[17];
  const float* W_l2  = (const float*)d_in[18];
  const float* b_l2  = (const float*)d_in[19];
  const float* Wd1   = (const float*)d_in[20];
  const float* bd1   = (const float*)d_in[21];
  const float* Wd2   = (const float*)d_in[22];
  const float* bd2   = (const float*)d_in[23];
  const float* Wo    = (const float*)d_in[24];
  const float* bo    = (const float*)d_in[25];
  float* outp = (float*)d_out;

  // workspace carve-up (~31 MB)
  __bf16* Z1T  = (__bf16*)d_ws;                     // 8*288*2048
  __bf16* Z2T  = Z1T + (size_t)Bc * 288 * Nn;       // 8*352*2048
  __bf16* ZpT  = Z2T + (size_t)Bc * 352 * Nn;       // 8*32*1024
  __bf16* Y1bf = ZpT + (size_t)Bc * 32 * Np;        // 8*2048*288
  float* pooled  = (float*)(Y1bf + (size_t)Bc * Nn * 288);  // 8*32
  float* p2      = pooled + Bc * 32;                // 8*352
  float* bias288 = p2 + Bc * 352;                   // 288
  float* biasg   = bias288 + 288;                   // 256

  hipMemsetAsync(pooled, 0, (Bc * 32 + Bc * 352) * sizeof(float), stream);

  build_bias_kernel<<<1, 544, 0, stream>>>(b_l1a, b_l1b, b_l2, bias288, biasg);
  build_z1t_kernel<<<(Bc * 288 * Nn) / 256, 256, 0, stream>>>(
      x_n, fg0, fg1, fg2, fg3, fg4, fg5, W_l1a, W_l1b, Z1T);
  build_zpt_kernel<<<(Bc * 32 * Np) / 256, 256, 0, stream>>>(x_p, W_l1a, ZpT);

  // phase 1: layer-1 main (Y1) + A_p (pooled), one dispatch, 384 blocks
  mega0_kernel<<<384, 256, 0, stream>>>(
      A_n, A_p, Z1T, ZpT, bias288, b_l1a + 96, Y1bf, pooled);

  build_z2t_kernel<<<dim3(Nn / 32, Bc), 256, 0, stream>>>(Y1bf, pooled, W_l2, Z2T);

  // phase 2: layer-2 A_n (256 cols) + ts/cs/s (32 each), one dispatch, 1024 blocks
  mega1_kernel<<<1024, 256, 0, stream>>>(
      A_n, A_ts, A_cs, A_s, Z2T, biasg, b_l2 + 32, p2);

  final_mlp_kernel<<<1, 128, 0, stream>>>(p2, Wd1, bd1, Wd2, bd2, Wo, bo, outp);
}